// Round 1
// baseline (1280.664 us; speedup 1.0000x reference)
//
#include <hip/hip_runtime.h>
#include <math.h>

#define Bn 16
#define Cc 256
#define HWsz 1024
#define Nrows 16384          // B*H*W
#define NE 8192
#define Kdim 256
#define SPLITS 4
#define TILES_PER_SPLIT ((NE / SPLITS) / 64)   // 32
#define BETAF 0.25f

// ---------------- kernel 1: cc[j] = sum_k codebook[j][k]^2 ----------------
__global__ __launch_bounds__(256) void cc_kernel(const float* __restrict__ cb,
                                                 float* __restrict__ cc) {
  int wave = threadIdx.x >> 6;
  int lane = threadIdx.x & 63;
  int row = blockIdx.x * 4 + wave;
  const float4 v = *(const float4*)(cb + (size_t)row * Kdim + lane * 4);
  float s = v.x * v.x + v.y * v.y + v.z * v.z + v.w * v.w;
  for (int off = 32; off; off >>= 1) s += __shfl_down(s, off);
  if (lane == 0) cc[row] = s;
}

// ---------------- kernel 2: tiled GEMM + per-row argmin over a code split --
// Grid: (256 row-tiles, SPLITS). Block 256 threads = 16(tx: code) x 16(ty: row).
// Each thread: 4 rows x 4 codes micro-tile. K chunks of 16, double-buffered LDS.
__global__ __launch_bounds__(256, 4) void vq_argmin_kernel(
    const float* __restrict__ z, const float* __restrict__ cb,
    const float* __restrict__ cc, float* __restrict__ pd, int* __restrict__ pj) {
  const int rowtile = blockIdx.x;          // 0..255
  const int split = blockIdx.y;            // 0..SPLITS-1
  const int b = rowtile >> 4;
  const int hw0 = (rowtile & 15) << 6;
  const float* zb = z + (size_t)b * (Cc * HWsz) + hw0;  // zb[k*HWsz + i]

  const int t = threadIdx.x;
  const int tx = t & 15;   // code dim
  const int ty = t >> 4;   // row dim

  __shared__ float As[2][16][64];
  __shared__ float Bs[2][16][64];
  __shared__ float zzs[64];
  __shared__ float redd[16][64];
  __shared__ int redj[16][64];

  // ---- zz[r] = sum_k z[r][k]^2 (rows of this tile) ----
  {
    int r = t & 63, q = t >> 6;
    float s = 0.f;
    for (int k = q * 64; k < q * 64 + 64; ++k) {
      float v = zb[(size_t)k * HWsz + r];
      s = fmaf(v, v, s);
    }
    redd[q][r] = s;
    __syncthreads();
    if (t < 64) zzs[t] = ((redd[0][t] + redd[1][t]) + redd[2][t]) + redd[3][t];
    __syncthreads();
  }

  float bd[4];
  int bj[4];
#pragma unroll
  for (int m = 0; m < 4; ++m) { bd[m] = INFINITY; bj[m] = 0; }

  const int code0 = split * (NE / SPLITS);
  int buf = 0;

  // preload (tile 0, kc 0)
  {
    int k = t >> 4, i = (t & 15) * 4;
    float4 a = *(const float4*)(zb + (size_t)k * HWsz + i);
    *(float4*)&As[0][k][i] = a;
    int j = t >> 2, kq = t & 3;
    float4 bv = *(const float4*)(cb + (size_t)(code0 + j) * Kdim + kq * 4);
    Bs[0][kq * 4 + 0][j] = bv.x;
    Bs[0][kq * 4 + 1][j] = bv.y;
    Bs[0][kq * 4 + 2][j] = bv.z;
    Bs[0][kq * 4 + 3][j] = bv.w;
  }
  __syncthreads();

  for (int tile = 0; tile < TILES_PER_SPLIT; ++tile) {
    const int cbase = code0 + tile * 64;
    float acc[4][4] = {};
    for (int kc = 0; kc < 16; ++kc) {
      const bool have = !(tile == TILES_PER_SPLIT - 1 && kc == 15);
      int nt = tile, nk = kc + 1;
      if (nk == 16) { nt = tile + 1; nk = 0; }
      float4 an, bn;
      if (have) {
        int k = t >> 4, i = (t & 15) * 4;
        an = *(const float4*)(zb + (size_t)(nk * 16 + k) * HWsz + i);
        int j = t >> 2, kq = t & 3;
        bn = *(const float4*)(cb + (size_t)(code0 + nt * 64 + j) * Kdim + nk * 16 + kq * 4);
      }
#pragma unroll
      for (int k = 0; k < 16; ++k) {
        const float4 a4 = *(const float4*)&As[buf][k][ty * 4];
        const float4 b4 = *(const float4*)&Bs[buf][k][tx * 4];
        acc[0][0] = fmaf(a4.x, b4.x, acc[0][0]);
        acc[0][1] = fmaf(a4.x, b4.y, acc[0][1]);
        acc[0][2] = fmaf(a4.x, b4.z, acc[0][2]);
        acc[0][3] = fmaf(a4.x, b4.w, acc[0][3]);
        acc[1][0] = fmaf(a4.y, b4.x, acc[1][0]);
        acc[1][1] = fmaf(a4.y, b4.y, acc[1][1]);
        acc[1][2] = fmaf(a4.y, b4.z, acc[1][2]);
        acc[1][3] = fmaf(a4.y, b4.w, acc[1][3]);
        acc[2][0] = fmaf(a4.z, b4.x, acc[2][0]);
        acc[2][1] = fmaf(a4.z, b4.y, acc[2][1]);
        acc[2][2] = fmaf(a4.z, b4.z, acc[2][2]);
        acc[2][3] = fmaf(a4.z, b4.w, acc[2][3]);
        acc[3][0] = fmaf(a4.w, b4.x, acc[3][0]);
        acc[3][1] = fmaf(a4.w, b4.y, acc[3][1]);
        acc[3][2] = fmaf(a4.w, b4.z, acc[3][2]);
        acc[3][3] = fmaf(a4.w, b4.w, acc[3][3]);
      }
      if (have) {
        int k = t >> 4, i = (t & 15) * 4;
        *(float4*)&As[buf ^ 1][k][i] = an;
        int j = t >> 2, kq = t & 3;
        Bs[buf ^ 1][kq * 4 + 0][j] = bn.x;
        Bs[buf ^ 1][kq * 4 + 1][j] = bn.y;
        Bs[buf ^ 1][kq * 4 + 2][j] = bn.z;
        Bs[buf ^ 1][kq * 4 + 3][j] = bn.w;
      }
      __syncthreads();
      buf ^= 1;
    }
    // epilogue: d = (zz + cc) - 2*acc, running argmin (j ascending per thread)
#pragma unroll
    for (int n = 0; n < 4; ++n) {
      const int j = cbase + tx * 4 + n;
      const float ccj = cc[j];
#pragma unroll
      for (int m = 0; m < 4; ++m) {
        const float tzc = zzs[ty * 4 + m] + ccj;
        const float d = tzc - 2.0f * acc[m][n];
        if (d < bd[m]) { bd[m] = d; bj[m] = j; }
      }
    }
  }

  // cross-thread reduction over the 16 tx lanes per row (tie -> lower idx)
#pragma unroll
  for (int m = 0; m < 4; ++m) {
    redd[tx][ty * 4 + m] = bd[m];
    redj[tx][ty * 4 + m] = bj[m];
  }
  __syncthreads();
  if (t < 64) {
    float d0 = redd[0][t];
    int j0 = redj[0][t];
    for (int x = 1; x < 16; ++x) {
      float d = redd[x][t];
      int j = redj[x][t];
      if (d < d0 || (d == d0 && j < j0)) { d0 = d; j0 = j; }
    }
    const int n = rowtile * 64 + t;
    pd[(size_t)split * Nrows + n] = d0;
    pj[(size_t)split * Nrows + n] = j0;
  }
}

// ---------------- kernel 3: combine splits, emit idx + counts --------------
__global__ __launch_bounds__(256) void vq_combine(const float* __restrict__ pd,
                                                  const int* __restrict__ pj,
                                                  int* __restrict__ idx_int,
                                                  float* __restrict__ out_idxf,
                                                  int* __restrict__ counts) {
  const int n = blockIdx.x * 256 + threadIdx.x;
  float d0 = pd[n];
  int j0 = pj[n];
  for (int s = 1; s < SPLITS; ++s) {
    float d = pd[(size_t)s * Nrows + n];
    int j = pj[(size_t)s * Nrows + n];
    if (d < d0 || (d == d0 && j < j0)) { d0 = d; j0 = j; }
  }
  idx_int[n] = j0;
  out_idxf[n] = (float)j0;
  atomicAdd(&counts[j0], 1);
}

// ---------------- kernel 4: gather zq (BCHW) + loss sum --------------------
__global__ __launch_bounds__(256) void vq_gather_loss(
    const float* __restrict__ z, const float* __restrict__ cb,
    const int* __restrict__ idx_int, float* __restrict__ outz,
    float* __restrict__ loss_sum) {
  const int g = blockIdx.x * 256 + threadIdx.x;  // one float4 group (b,c,hw4)
  const int hw4 = g & 255;
  const int c = (g >> 8) & 255;
  const int b = g >> 16;
  const int n = b * HWsz + hw4 * 4;
  const float4 zv = *(const float4*)(z + (size_t)g * 4);
  const int4 j4 = *(const int4*)(idx_int + n);
  float4 q;
  q.x = cb[(size_t)j4.x * Kdim + c];
  q.y = cb[(size_t)j4.y * Kdim + c];
  q.z = cb[(size_t)j4.z * Kdim + c];
  q.w = cb[(size_t)j4.w * Kdim + c];
  *(float4*)(outz + (size_t)g * 4) = q;
  float dx = q.x - zv.x, dy = q.y - zv.y, dz = q.z - zv.z, dw = q.w - zv.w;
  float s = dx * dx + dy * dy + dz * dz + dw * dw;
  for (int off = 32; off; off >>= 1) s += __shfl_down(s, off);
  __shared__ float ws4[4];
  if ((threadIdx.x & 63) == 0) ws4[threadIdx.x >> 6] = s;
  __syncthreads();
  if (threadIdx.x == 0) atomicAdd(loss_sum, (ws4[0] + ws4[1]) + (ws4[2] + ws4[3]));
}

// ---------------- kernel 5: scalars (loss, perplexity) ---------------------
__global__ __launch_bounds__(256) void vq_final(const int* __restrict__ counts,
                                                const float* __restrict__ loss_sum,
                                                float* __restrict__ out_sc) {
  float h = 0.f;
  for (int i = threadIdx.x; i < NE; i += 256) {
    float p = (float)counts[i] * (1.0f / 16384.0f);
    h += p * logf(p + 1e-10f);
  }
  for (int off = 32; off; off >>= 1) h += __shfl_down(h, off);
  __shared__ float hs[4];
  if ((threadIdx.x & 63) == 0) hs[threadIdx.x >> 6] = h;
  __syncthreads();
  if (threadIdx.x == 0) {
    float H = (hs[0] + hs[1]) + (hs[2] + hs[3]);
    float m = loss_sum[0] * (1.0f / 4194304.0f);
    out_sc[0] = m + BETAF * m;   // embedding_loss + BETA*commitment_loss (equal fwd)
    out_sc[1] = expf(-H);
  }
}

extern "C" void kernel_launch(void* const* d_in, const int* in_sizes, int n_in,
                              void* d_out, int out_size, void* d_ws, size_t ws_size,
                              hipStream_t stream) {
  const float* z = (const float*)d_in[0];
  const float* cb = (const float*)d_in[1];
  float* out = (float*)d_out;
  float* out_zq = out;                     // 4194304
  float* out_sc = out + 4194304;           // loss, perplexity
  float* out_idx = out + 4194306;          // 16384 (idx as float)

  char* w = (char*)d_ws;
  float* cc = (float*)w;        w += (size_t)NE * 4;
  float* pd = (float*)w;        w += (size_t)SPLITS * Nrows * 4;
  int* pj = (int*)w;            w += (size_t)SPLITS * Nrows * 4;
  int* idx_int = (int*)w;       w += (size_t)Nrows * 4;
  int* counts = (int*)w;        w += (size_t)NE * 4;
  float* loss_sum = (float*)w;  w += 4;

  hipMemsetAsync(counts, 0, (size_t)NE * 4, stream);
  hipMemsetAsync(loss_sum, 0, 4, stream);

  cc_kernel<<<NE / 4, 256, 0, stream>>>(cb, cc);
  dim3 g2(256, SPLITS);
  vq_argmin_kernel<<<g2, 256, 0, stream>>>(z, cb, cc, pd, pj);
  vq_combine<<<Nrows / 256, 256, 0, stream>>>(pd, pj, idx_int, out_idx, counts);
  vq_gather_loss<<<4096, 256, 0, stream>>>(z, cb, idx_int, out_zq, loss_sum);
  vq_final<<<1, 256, 0, stream>>>(counts, loss_sum, out_sc);
}